// Round 3
// baseline (493.239 us; speedup 1.0000x reference)
//
#include <hip/hip_runtime.h>

#define T_ 2048
#define S_ 2048
#define H_ 16
#define DQK 192
#define DV_ 128
#define CLR_ 512
#define DIM_ 2048
#define SCALE_ 0.07216878364870322f

typedef unsigned short u16;
typedef unsigned int u32;
typedef __attribute__((ext_vector_type(8))) u16 u16x8;
typedef __attribute__((ext_vector_type(4))) u16 u16x4;
typedef __attribute__((ext_vector_type(8))) __bf16 bf16x8;
typedef __attribute__((ext_vector_type(4))) float f32x4;

// round-to-nearest-even f32 -> bf16 (no NaN in this problem)
__device__ __forceinline__ u16 f2bf(float f) {
  u32 x = __builtin_bit_cast(u32, f);
  u32 r = x + 0x7fffu + ((x >> 16) & 1u);
  return (u16)(r >> 16);
}

__device__ __forceinline__ f32x4 mfma16(u16x8 a, u16x8 b, f32x4 c) {
  return __builtin_amdgcn_mfma_f32_16x16x32_bf16(
      __builtin_bit_cast(bf16x8, a), __builtin_bit_cast(bf16x8, b), c, 0, 0, 0);
}

// ---------------- kernel 1: pack Q, K-pe, and bf16-convert kv/wkv/wo ----------------
__global__ __launch_bounds__(256) void k_build(
    const float* __restrict__ qn, const float* __restrict__ qp,
    const float* __restrict__ pe, const float* __restrict__ kv,
    const float* __restrict__ wkv, const float* __restrict__ wo,
    u16* __restrict__ Qc, u16* __restrict__ Kc,
    u16* __restrict__ kvb, u16* __restrict__ wkvb, u16* __restrict__ wob) {
  u32 gid = blockIdx.x * 256u + threadIdx.x;
  u32 stride = gridDim.x * 256u;

  // Q pack: [H][T][192] bf16, from qn[t][h][128] ++ qp[t][h][64]; float4 chunks
  const u32 NQ = H_ * T_ * 48u;
  for (u32 i = gid; i < NQ; i += stride) {
    u32 j4 = i % 48u;
    u32 th = i / 48u;
    u32 t = th & (T_ - 1);
    u32 h = th >> 11;
    float4 v = (j4 < 32u) ? *(const float4*)(qn + ((size_t)t * H_ + h) * 128 + j4 * 4)
                          : *(const float4*)(qp + ((size_t)t * H_ + h) * 64 + (j4 - 32u) * 4);
    u16x4 o = {f2bf(v.x), f2bf(v.y), f2bf(v.z), f2bf(v.w)};
    *(u16x4*)(Qc + (size_t)th * DQK + j4 * 4) = o;
  }
  // pe -> Kc[h][s][128:192]
  const u32 NP = H_ * S_ * 16u;
  for (u32 i = gid; i < NP; i += stride) {
    u32 j4 = i & 15u;
    u32 s = (i >> 4) & (S_ - 1);
    u32 h = i >> 15;
    float4 v = *(const float4*)(pe + (size_t)s * 64 + j4 * 4);
    u16x4 o = {f2bf(v.x), f2bf(v.y), f2bf(v.z), f2bf(v.w)};
    *(u16x4*)(Kc + ((size_t)h * S_ + s) * DQK + 128 + j4 * 4) = o;
  }
  // straight f32 -> bf16 conversions
  const u32 NKV = (2048u * 512u) / 4u;
  for (u32 i = gid; i < NKV; i += stride) {
    float4 v = *(const float4*)(kv + (size_t)i * 4);
    u16x4 o = {f2bf(v.x), f2bf(v.y), f2bf(v.z), f2bf(v.w)};
    *(u16x4*)(kvb + (size_t)i * 4) = o;
  }
  const u32 NW = (4096u * 512u) / 4u;
  for (u32 i = gid; i < NW; i += stride) {
    float4 v = *(const float4*)(wkv + (size_t)i * 4);
    u16x4 o = {f2bf(v.x), f2bf(v.y), f2bf(v.z), f2bf(v.w)};
    *(u16x4*)(wkvb + (size_t)i * 4) = o;
  }
  const u32 NO = (2048u * 2048u) / 4u;
  for (u32 i = gid; i < NO; i += stride) {
    float4 v = *(const float4*)(wo + (size_t)i * 4);
    u16x4 o = {f2bf(v.x), f2bf(v.y), f2bf(v.z), f2bf(v.w)};
    *(u16x4*)(wob + (size_t)i * 4) = o;
  }
}

// ---------------- kernel 2: expand GEMM: kv(2048x512) @ wkv^T(4096x512), bf16 in ----------------
// n = h*256 + d ; d<128 -> K_nope[h][s][d] ; d>=128 -> Vt[h][d-128][s]
__global__ __launch_bounds__(256) void k_expand(
    const u16* __restrict__ kvb, const u16* __restrict__ wkvb,
    u16* __restrict__ Kc, u16* __restrict__ Vt) {
  __shared__ u16 Al[128][72];
  __shared__ u16 Bl[128][72];
  int tid = threadIdx.x;
  int wave = tid >> 6, lane = tid & 63, lr = lane & 15, lq = lane >> 4;
  int wm = wave >> 1, wn = wave & 1;
  int s0 = blockIdx.x * 128, n0 = blockIdx.y * 128;
  f32x4 acc[4][4] = {};
  for (int kc = 0; kc < CLR_; kc += 64) {
    __syncthreads();
#pragma unroll
    for (int i = 0; i < 4; ++i) {  // 128x64 bf16 each matrix
      int ch = tid + 256 * i;
      int r = ch >> 3, c = (ch & 7) * 8;
      *(u16x8*)&Al[r][c] = *(const u16x8*)(kvb + (size_t)(s0 + r) * CLR_ + kc + c);
      *(u16x8*)&Bl[r][c] = *(const u16x8*)(wkvb + (size_t)(n0 + r) * CLR_ + kc + c);
    }
    __syncthreads();
#pragma unroll
    for (int ks = 0; ks < 2; ++ks) {
      u16x8 a[4], b[4];
#pragma unroll
      for (int m = 0; m < 4; ++m) a[m] = *(const u16x8*)&Al[wm * 64 + m * 16 + lr][ks * 32 + lq * 8];
#pragma unroll
      for (int n = 0; n < 4; ++n) b[n] = *(const u16x8*)&Bl[wn * 64 + n * 16 + lr][ks * 32 + lq * 8];
#pragma unroll
      for (int m = 0; m < 4; ++m)
#pragma unroll
        for (int n = 0; n < 4; ++n) acc[m][n] = mfma16(a[m], b[n], acc[m][n]);
    }
  }
#pragma unroll
  for (int m = 0; m < 4; ++m) {
    int s = s0 + wm * 64 + m * 16 + lq * 4;
#pragma unroll
    for (int n = 0; n < 4; ++n) {
      int nn = n0 + wn * 64 + n * 16 + lr;
      int h = nn >> 8, cc = nn & 255;
#pragma unroll
      for (int r = 0; r < 4; ++r) {
        u16 bv = f2bf(acc[m][n][r]);
        if (cc < 128) Kc[((size_t)h * S_ + s + r) * DQK + cc] = bv;
        else          Vt[((size_t)h * 128 + (cc - 128)) * S_ + s + r] = bv;
      }
    }
  }
}

// ---------------- kernel 3: causal flash attention (no K/V LDS staging) ----------------
// grid (T/64, H), launched reversed so diagonal (long) blocks start first.
// 4 waves x 16 q-rows; KV tile 64; K/V fragments read direct from global (L1/L2-resident).
// Only LDS use: per-wave P round-trip (wave-local lgkmcnt sync, NO block barriers in loop).
__global__ __launch_bounds__(256) void k_attn(
    const u16* __restrict__ Qc, const u16* __restrict__ Kc,
    const u16* __restrict__ Vt, u16* __restrict__ Ob,
    const int* __restrict__ pclp) {
  __shared__ u16 Pl[4][16][72];
  int h = blockIdx.y;
  int t0 = (int)(gridDim.x - 1u - blockIdx.x) * 64;
  int pcl = *pclp;
  int tid = threadIdx.x;
  int wave = tid >> 6, lane = tid & 63, lr = lane & 15, lq = lane >> 4;

  u16x8 qf[6];
  const u16* qb = Qc + ((size_t)h * T_ + t0 + wave * 16 + lr) * DQK;
#pragma unroll
  for (int k = 0; k < 6; ++k) qf[k] = *(const u16x8*)(qb + k * 32 + lq * 8);

  f32x4 acc[8] = {};
  float dsum[4] = {0.f, 0.f, 0.f, 0.f};

  long smax = (long)t0 + 63 + (long)pcl;
  if (smax > (long)(S_ - 1)) smax = S_ - 1;
  int nkv = (int)(smax >> 6) + 1;

  const u16* kb_base = Kc + (size_t)h * S_ * DQK + (size_t)lr * DQK + lq * 8;
  const u16* vb_base = Vt + (size_t)h * 128 * S_ + (size_t)lr * S_ + lq * 8;
  int tg = t0 + wave * 16 + lq * 4 + pcl;

  for (int kt = 0; kt < nkv; ++kt) {
    int s0 = kt * 64;

    // QK^T: K fragments direct from global (rows s0+nf*16+lr, 64B-coalesced)
    f32x4 lg[4] = {};
    const u16* kp = kb_base + (size_t)s0 * DQK;
#pragma unroll
    for (int ks = 0; ks < 6; ++ks) {
#pragma unroll
      for (int nf = 0; nf < 4; ++nf) {
        u16x8 b = *(const u16x8*)(kp + (size_t)nf * (16 * DQK) + ks * 32);
        lg[nf] = mfma16(qf[ks], b, lg[nf]);
      }
    }

    // mask + exp + P to wave-private LDS (D-layout -> A-layout transpose)
#pragma unroll
    for (int nf = 0; nf < 4; ++nf) {
      int sg = s0 + nf * 16 + lr;
#pragma unroll
      for (int r = 0; r < 4; ++r) {
        float e = __expf(lg[nf][r] * SCALE_);
        float p = (sg <= tg + r) ? e : 0.f;
        dsum[r] += p;
        Pl[wave][lq * 4 + r][nf * 16 + lr] = f2bf(p);
      }
    }
    // wave-local: Pl is per-wave, no block barrier needed
    asm volatile("s_waitcnt lgkmcnt(0)" ::: "memory");
    __builtin_amdgcn_sched_barrier(0);
    u16x8 pa0 = *(const u16x8*)&Pl[wave][lr][lq * 8];
    u16x8 pa1 = *(const u16x8*)&Pl[wave][lr][32 + lq * 8];

    // PV: V fragments direct from global ([h][d][s] rows, 64B-coalesced)
    const u16* vp = vb_base + s0;
#pragma unroll
    for (int db = 0; db < 8; ++db) {
      u16x8 v0 = *(const u16x8*)(vp + (size_t)db * (16 * S_));
      u16x8 v1 = *(const u16x8*)(vp + (size_t)db * (16 * S_) + 32);
      acc[db] = mfma16(pa0, v0, acc[db]);
      acc[db] = mfma16(pa1, v1, acc[db]);
    }
  }

#pragma unroll
  for (int r = 0; r < 4; ++r) {
    float s = dsum[r];
#pragma unroll
    for (int m = 1; m < 16; m <<= 1) s += __shfl_xor(s, m, 64);
    float inv = 1.f / s;
    int t = t0 + wave * 16 + lq * 4 + r;
#pragma unroll
    for (int db = 0; db < 8; ++db)
      Ob[(size_t)t * (H_ * DV_) + h * DV_ + db * 16 + lr] = f2bf(acc[db][r] * inv);
  }
}

// ---------------- kernel 4: output projection (2048x2048x2048), bf16 in ----------------
__global__ __launch_bounds__(256) void k_proj(
    const u16* __restrict__ A, const u16* __restrict__ wob,
    float* __restrict__ out) {
  __shared__ u16 Al[128][72];
  __shared__ u16 Bl[128][72];
  int tid = threadIdx.x;
  int wave = tid >> 6, lane = tid & 63, lr = lane & 15, lq = lane >> 4;
  int wm = wave >> 1, wn = wave & 1;
  int t0 = blockIdx.x * 128, o0 = blockIdx.y * 128;
  f32x4 acc[4][4] = {};
  for (int kc = 0; kc < DIM_; kc += 64) {
    __syncthreads();
#pragma unroll
    for (int i = 0; i < 4; ++i) {
      int ch = tid + 256 * i;
      int r = ch >> 3, c = (ch & 7) * 8;
      *(u16x8*)&Al[r][c] = *(const u16x8*)(A + (size_t)(t0 + r) * 2048 + kc + c);
      *(u16x8*)&Bl[r][c] = *(const u16x8*)(wob + (size_t)(o0 + r) * 2048 + kc + c);
    }
    __syncthreads();
#pragma unroll
    for (int ks = 0; ks < 2; ++ks) {
      u16x8 a[4], b[4];
#pragma unroll
      for (int m = 0; m < 4; ++m) a[m] = *(const u16x8*)&Al[wm * 64 + m * 16 + lr][ks * 32 + lq * 8];
#pragma unroll
      for (int n = 0; n < 4; ++n) b[n] = *(const u16x8*)&Bl[wn * 64 + n * 16 + lr][ks * 32 + lq * 8];
#pragma unroll
      for (int m = 0; m < 4; ++m)
#pragma unroll
        for (int n = 0; n < 4; ++n) acc[m][n] = mfma16(a[m], b[n], acc[m][n]);
    }
  }
#pragma unroll
  for (int m = 0; m < 4; ++m) {
    int t = t0 + wm * 64 + m * 16 + lq * 4;
#pragma unroll
    for (int n = 0; n < 4; ++n) {
      int o = o0 + wn * 64 + n * 16 + lr;
#pragma unroll
      for (int r = 0; r < 4; ++r)
        out[(size_t)(t + r) * DIM_ + o] = acc[m][n][r];
    }
  }
}

extern "C" void kernel_launch(void* const* d_in, const int* in_sizes, int n_in,
                              void* d_out, int out_size, void* d_ws, size_t ws_size,
                              hipStream_t stream) {
  const float* qn  = (const float*)d_in[0];
  const float* qp  = (const float*)d_in[1];
  const float* kv  = (const float*)d_in[2];
  const float* pe  = (const float*)d_in[3];
  const float* wkv = (const float*)d_in[4];
  const float* wo  = (const float*)d_in[5];
  const int*   pcl = (const int*)d_in[6];
  float* out = (float*)d_out;

  char* ws = (char*)d_ws;
  // workspace layout (~54 MiB)
  u16* Qc   = (u16*)(ws);                 // [H][T][192]  12,582,912 B
  u16* Kc   = (u16*)(ws + 12582912);      // [H][S][192]  12,582,912 B
  u16* Vt   = (u16*)(ws + 25165824);      // [H][128][S]   8,388,608 B
  u16* Ob   = (u16*)(ws + 33554432);      // [T][H*128]    8,388,608 B
  u16* kvb  = (u16*)(ws + 41943040);      // [S][512]      2,097,152 B
  u16* wkvb = (u16*)(ws + 44040192);      // [4096][512]   4,194,304 B
  u16* wob  = (u16*)(ws + 48234496);      // [2048][2048]  8,388,608 B

  k_build<<<2048, 256, 0, stream>>>(qn, qp, pe, kv, wkv, wo, Qc, Kc, kvb, wkvb, wob);
  k_expand<<<dim3(16, 32), 256, 0, stream>>>(kvb, wkvb, Kc, Vt);
  k_attn<<<dim3(32, 16), 256, 0, stream>>>(Qc, Kc, Vt, Ob, pcl);
  k_proj<<<dim3(16, 16), 256, 0, stream>>>(Ob, wob, out);
}

// Round 5
// 278.679 us; speedup vs baseline: 1.7699x; 1.7699x over previous
//
#include <hip/hip_runtime.h>

#define T_ 2048
#define S_ 2048
#define H_ 16
#define DQK 192
#define DV_ 128
#define CLR_ 512
#define DIM_ 2048
#define SCALE_ 0.07216878364870322f

typedef unsigned short u16;
typedef unsigned int u32;
typedef __attribute__((ext_vector_type(8))) u16 u16x8;
typedef __attribute__((ext_vector_type(4))) u16 u16x4;
typedef __attribute__((ext_vector_type(8))) __bf16 bf16x8;
typedef __attribute__((ext_vector_type(4))) float f32x4;

__device__ __forceinline__ u16 f2bf(float f) {
  u32 x = __builtin_bit_cast(u32, f);
  u32 r = x + 0x7fffu + ((x >> 16) & 1u);
  return (u16)(r >> 16);
}

__device__ __forceinline__ f32x4 mfma16(u16x8 a, u16x8 b, f32x4 c) {
  return __builtin_amdgcn_mfma_f32_16x16x32_bf16(
      __builtin_bit_cast(bf16x8, a), __builtin_bit_cast(bf16x8, b), c, 0, 0, 0);
}

// async global->LDS, 16B per lane; lds base must be wave-uniform (HW adds lane*16)
__device__ __forceinline__ void gload16(const u16* g, const u16* lds_base) {
  auto gp = reinterpret_cast<const __attribute__((address_space(1))) unsigned int*>(
      reinterpret_cast<uintptr_t>(g));
  auto lp = reinterpret_cast<__attribute__((address_space(3))) unsigned int*>(
      reinterpret_cast<uintptr_t>(lds_base));
  __builtin_amdgcn_global_load_lds(gp, lp, 16, 0, 0);
}

// ---------------- kernel 1: pack Q, K-pe, bf16-convert kv/wkv/wo ----------------
__global__ __launch_bounds__(256) void k_build(
    const float* __restrict__ qn, const float* __restrict__ qp,
    const float* __restrict__ pe, const float* __restrict__ kv,
    const float* __restrict__ wkv, const float* __restrict__ wo,
    u16* __restrict__ Qc, u16* __restrict__ Kc,
    u16* __restrict__ kvb, u16* __restrict__ wkvb, u16* __restrict__ wob) {
  u32 gid = blockIdx.x * 256u + threadIdx.x;
  u32 stride = gridDim.x * 256u;

  const u32 NQ = H_ * T_ * 48u;
  for (u32 i = gid; i < NQ; i += stride) {
    u32 j4 = i % 48u;
    u32 th = i / 48u;
    u32 t = th & (T_ - 1);
    u32 h = th >> 11;
    float4 v = (j4 < 32u) ? *(const float4*)(qn + ((size_t)t * H_ + h) * 128 + j4 * 4)
                          : *(const float4*)(qp + ((size_t)t * H_ + h) * 64 + (j4 - 32u) * 4);
    u16x4 o = {f2bf(v.x), f2bf(v.y), f2bf(v.z), f2bf(v.w)};
    *(u16x4*)(Qc + (size_t)th * DQK + j4 * 4) = o;
  }
  const u32 NP = H_ * S_ * 16u;
  for (u32 i = gid; i < NP; i += stride) {
    u32 j4 = i & 15u;
    u32 s = (i >> 4) & (S_ - 1);
    u32 h = i >> 15;
    float4 v = *(const float4*)(pe + (size_t)s * 64 + j4 * 4);
    u16x4 o = {f2bf(v.x), f2bf(v.y), f2bf(v.z), f2bf(v.w)};
    *(u16x4*)(Kc + ((size_t)h * S_ + s) * DQK + 128 + j4 * 4) = o;
  }
  const u32 NKV = (2048u * 512u) / 4u;
  for (u32 i = gid; i < NKV; i += stride) {
    float4 v = *(const float4*)(kv + (size_t)i * 4);
    u16x4 o = {f2bf(v.x), f2bf(v.y), f2bf(v.z), f2bf(v.w)};
    *(u16x4*)(kvb + (size_t)i * 4) = o;
  }
  const u32 NW = (4096u * 512u) / 4u;
  for (u32 i = gid; i < NW; i += stride) {
    float4 v = *(const float4*)(wkv + (size_t)i * 4);
    u16x4 o = {f2bf(v.x), f2bf(v.y), f2bf(v.z), f2bf(v.w)};
    *(u16x4*)(wkvb + (size_t)i * 4) = o;
  }
  const u32 NO = (2048u * 2048u) / 4u;
  for (u32 i = gid; i < NO; i += stride) {
    float4 v = *(const float4*)(wo + (size_t)i * 4);
    u16x4 o = {f2bf(v.x), f2bf(v.y), f2bf(v.z), f2bf(v.w)};
    *(u16x4*)(wob + (size_t)i * 4) = o;
  }
}

// ---------------- kernel 2: expand GEMM 2048x4096x512, 2-phase global_load_lds ----------------
__global__ __launch_bounds__(256) void k_expand(
    const u16* __restrict__ kvb, const u16* __restrict__ wkvb,
    u16* __restrict__ Kc, u16* __restrict__ Vt) {
  __shared__ __align__(16) u16 Al[2 * 128 * 64];
  __shared__ __align__(16) u16 Bl[2 * 128 * 64];
  int tid = threadIdx.x;
  int wave = tid >> 6, lane = tid & 63, lr = lane & 15, lq = lane >> 4;
  int wm = wave >> 1, wn = wave & 1;
  int s0 = blockIdx.x * 128, n0 = blockIdx.y * 128;
  f32x4 acc[4][4] = {};

  auto stage = [&](int buf, int kc) {
#pragma unroll
    for (int i = 0; i < 4; ++i) {
      int ch = tid + 256 * i;
      int r = ch >> 3, c8 = (ch & 7) * 8;
      const u16* lbA = Al + buf * 8192 + wave * 512 + i * 2048;  // bytes: wave*1024+i*4096
      const u16* lbB = Bl + buf * 8192 + wave * 512 + i * 2048;
      gload16(kvb + (size_t)(s0 + r) * CLR_ + kc + c8, lbA);
      gload16(wkvb + (size_t)(n0 + r) * CLR_ + kc + c8, lbB);
    }
  };

  stage(0, 0);
  __syncthreads();
  int buf = 0;
  const int nt = CLR_ / 64;
  for (int t = 0; t < nt; ++t) {
    if (t + 1 < nt) stage(buf ^ 1, (t + 1) * 64);
#pragma unroll
    for (int ks = 0; ks < 2; ++ks) {
      u16x8 a[4], b[4];
#pragma unroll
      for (int m = 0; m < 4; ++m)
        a[m] = *(const u16x8*)&Al[buf * 8192 + (wm * 64 + m * 16 + lr) * 64 + ks * 32 + lq * 8];
#pragma unroll
      for (int n = 0; n < 4; ++n)
        b[n] = *(const u16x8*)&Bl[buf * 8192 + (wn * 64 + n * 16 + lr) * 64 + ks * 32 + lq * 8];
#pragma unroll
      for (int m = 0; m < 4; ++m)
#pragma unroll
        for (int n = 0; n < 4; ++n) acc[m][n] = mfma16(a[m], b[n], acc[m][n]);
    }
    __syncthreads();
    buf ^= 1;
  }
#pragma unroll
  for (int m = 0; m < 4; ++m) {
    int s = s0 + wm * 64 + m * 16 + lq * 4;
#pragma unroll
    for (int n = 0; n < 4; ++n) {
      int nn = n0 + wn * 64 + n * 16 + lr;
      int h = nn >> 8, cc = nn & 255;
#pragma unroll
      for (int r = 0; r < 4; ++r) {
        u16 bv = f2bf(acc[m][n][r]);
        if (cc < 128) Kc[((size_t)h * S_ + s + r) * DQK + cc] = bv;
        else          Vt[((size_t)h * 128 + (cc - 128)) * S_ + s + r] = bv;
      }
    }
  }
}

// ---------------- kernel 3: causal flash attention, 8 waves, even/odd KV split ----------------
// grid (32,16). Block: 8 waves; waves g=wave&3 own 16 q-rows, ep=wave>>2 picks even/odd 32-s tile.
// K pair (64 s x 192) double-buffered in padded LDS (reg-staged: load early, write late).
// V direct from global. P round-trip wave-local. ONE barrier per 64-s phase.
__global__ __launch_bounds__(512, 4) void k_attn(
    const u16* __restrict__ Qc, const u16* __restrict__ Kc,
    const u16* __restrict__ Vt, u16* __restrict__ Ob,
    const int* __restrict__ pclp) {
  __shared__ __align__(16) u16 Kl[2][64][200];
  __shared__ __align__(16) u16 Pl[8][16][40];
  int h = blockIdx.y;
  // per-CU causal balance: co-resident blocks (same bx, h vs h+8) sum to ~33 phases
  int qt = ((h >> 3) & 1) ? (int)blockIdx.x : (int)(31 - blockIdx.x);
  int t0 = qt * 64;
  int pcl = *pclp;
  int tid = threadIdx.x;
  int wave = tid >> 6, lane = tid & 63, lr = lane & 15, lq = lane >> 4;
  int g = wave & 3, ep = wave >> 2;

  u16x8 qf[6];
  const u16* qb = Qc + ((size_t)h * T_ + t0 + g * 16 + lr) * DQK;
#pragma unroll
  for (int k = 0; k < 6; ++k) qf[k] = *(const u16x8*)(qb + k * 32 + lq * 8);

  f32x4 acc[8] = {};
  float dsum[4] = {0.f, 0.f, 0.f, 0.f};

  long smax = (long)t0 + 63 + (long)pcl;
  if (smax > (long)(S_ - 1)) smax = S_ - 1;
  int np = (int)(smax >> 6) + 1;  // phases of 64 s (pair of 32-tiles)

  const u16* kc_base = Kc + (size_t)h * S_ * DQK;
  const u16* vb = Vt + (size_t)h * 128 * S_ + (size_t)lr * S_ + lq * 8;
  int tg = t0 + g * 16 + lq * 4 + pcl;

  // prologue: stage pair 0
  u16x8 gk[3];
#pragma unroll
  for (int i = 0; i < 3; ++i) {
    int ch = tid + 512 * i;
    int r = ch / 24, c = ch % 24;
    gk[i] = *(const u16x8*)(kc_base + (size_t)r * DQK + c * 8);
  }
#pragma unroll
  for (int i = 0; i < 3; ++i) {
    int ch = tid + 512 * i;
    int r = ch / 24, c = ch % 24;
    *(u16x8*)&Kl[0][r][c * 8] = gk[i];
  }
  __syncthreads();

  int buf = 0;
  for (int p = 0; p < np; ++p) {
    int sp0 = p * 64;
    bool more = (p + 1 < np);
    // issue next-pair loads early (consumed at phase end)
    if (more) {
#pragma unroll
      for (int i = 0; i < 3; ++i) {
        int ch = tid + 512 * i;
        int r = ch / 24, c = ch % 24;
        gk[i] = *(const u16x8*)(kc_base + (size_t)(sp0 + 64 + r) * DQK + c * 8);
      }
    }
    int s0v = sp0 + ep * 32;

    // QK^T from LDS (row pad 400B rotates banks; 2-way max)
    f32x4 lg[2] = {};
#pragma unroll
    for (int ks = 0; ks < 6; ++ks) {
#pragma unroll
      for (int nf = 0; nf < 2; ++nf) {
        u16x8 b = *(const u16x8*)&Kl[buf][ep * 32 + nf * 16 + lr][ks * 32 + lq * 8];
        lg[nf] = mfma16(qf[ks], b, lg[nf]);
      }
    }

    // softmax partial + P round-trip (wave-local)
#pragma unroll
    for (int nf = 0; nf < 2; ++nf) {
      int sg = s0v + nf * 16 + lr;
#pragma unroll
      for (int r = 0; r < 4; ++r) {
        float e = __expf(lg[nf][r] * SCALE_);
        float pv = (sg <= tg + r) ? e : 0.f;
        dsum[r] += pv;
        Pl[wave][lq * 4 + r][nf * 16 + lr] = f2bf(pv);
      }
    }
    asm volatile("s_waitcnt lgkmcnt(0)" ::: "memory");
    __builtin_amdgcn_sched_barrier(0);
    u16x8 pa = *(const u16x8*)&Pl[wave][lr][lq * 8];

    // PV: V direct from global (L1/L2-resident, shared across waves)
#pragma unroll
    for (int db = 0; db < 8; ++db) {
      u16x8 v = *(const u16x8*)(vb + (size_t)(db * 16) * S_ + s0v);
      acc[db] = mfma16(pa, v, acc[db]);
    }

    // write next pair late, single barrier
    if (more) {
#pragma unroll
      for (int i = 0; i < 3; ++i) {
        int ch = tid + 512 * i;
        int r = ch / 24, c = ch % 24;
        *(u16x8*)&Kl[buf ^ 1][r][c * 8] = gk[i];
      }
    }
    __syncthreads();
    buf ^= 1;
  }

  // combine even/odd halves (reuse Kl as f32 scratch)
  float* comb = (float*)&Kl[0][0][0];
  if (ep == 1) {
    float* dst = comb + (size_t)(g * 64 + lane) * 36;
#pragma unroll
    for (int db = 0; db < 8; ++db) *(f32x4*)(dst + db * 4) = acc[db];
#pragma unroll
    for (int r = 0; r < 4; ++r) dst[32 + r] = dsum[r];
  }
  __syncthreads();
  if (ep == 0) {
    const float* src = comb + (size_t)(g * 64 + lane) * 36;
#pragma unroll
    for (int db = 0; db < 8; ++db) acc[db] += *(const f32x4*)(src + db * 4);
#pragma unroll
    for (int r = 0; r < 4; ++r) dsum[r] += src[32 + r];
#pragma unroll
    for (int r = 0; r < 4; ++r) {
      float s = dsum[r];
#pragma unroll
      for (int m = 1; m < 16; m <<= 1) s += __shfl_xor(s, m, 64);
      float inv = 1.f / s;
      int t = t0 + g * 16 + lq * 4 + r;
#pragma unroll
      for (int db = 0; db < 8; ++db)
        Ob[(size_t)t * (H_ * DV_) + h * DV_ + db * 16 + lr] = f2bf(acc[db][r] * inv);
    }
  }
}

// ---------------- kernel 4: output projection 2048x2048x2048, tile 64x128, 2-phase ----------------
__global__ __launch_bounds__(256) void k_proj(
    const u16* __restrict__ A, const u16* __restrict__ wob,
    float* __restrict__ out) {
  __shared__ __align__(16) u16 Al[2 * 64 * 64];
  __shared__ __align__(16) u16 Bl[2 * 128 * 64];
  int tid = threadIdx.x;
  int wave = tid >> 6, lane = tid & 63, lr = lane & 15, lq = lane >> 4;
  int wm = wave >> 1, wn = wave & 1;
  int t0 = blockIdx.x * 64, o0 = blockIdx.y * 128;
  f32x4 acc[2][4] = {};

  auto stage = [&](int buf, int kc) {
#pragma unroll
    for (int i = 0; i < 2; ++i) {
      int ch = tid + 256 * i;
      int r = ch >> 3, c8 = (ch & 7) * 8;
      const u16* lbA = Al + buf * 4096 + wave * 512 + i * 2048;
      gload16(A + (size_t)(t0 + r) * DIM_ + kc + c8, lbA);
    }
#pragma unroll
    for (int i = 0; i < 4; ++i) {
      int ch = tid + 256 * i;
      int r = ch >> 3, c8 = (ch & 7) * 8;
      const u16* lbB = Bl + buf * 8192 + wave * 512 + i * 2048;
      gload16(wob + (size_t)(o0 + r) * DIM_ + kc + c8, lbB);
    }
  };

  stage(0, 0);
  __syncthreads();
  int buf = 0;
  const int nt = DIM_ / 64;
  for (int t = 0; t < nt; ++t) {
    if (t + 1 < nt) stage(buf ^ 1, (t + 1) * 64);
#pragma unroll
    for (int ks = 0; ks < 2; ++ks) {
      u16x8 a[2], b[4];
#pragma unroll
      for (int m = 0; m < 2; ++m)
        a[m] = *(const u16x8*)&Al[buf * 4096 + (wm * 32 + m * 16 + lr) * 64 + ks * 32 + lq * 8];
#pragma unroll
      for (int n = 0; n < 4; ++n)
        b[n] = *(const u16x8*)&Bl[buf * 8192 + (wn * 64 + n * 16 + lr) * 64 + ks * 32 + lq * 8];
#pragma unroll
      for (int m = 0; m < 2; ++m)
#pragma unroll
        for (int n = 0; n < 4; ++n) acc[m][n] = mfma16(a[m], b[n], acc[m][n]);
    }
    __syncthreads();
    buf ^= 1;
  }
#pragma unroll
  for (int m = 0; m < 2; ++m) {
    int t = t0 + wm * 32 + m * 16 + lq * 4;
#pragma unroll
    for (int n = 0; n < 4; ++n) {
      int o = o0 + wn * 64 + n * 16 + lr;
#pragma unroll
      for (int r = 0; r < 4; ++r)
        out[(size_t)(t + r) * DIM_ + o] = acc[m][n][r];
    }
  }
}

extern "C" void kernel_launch(void* const* d_in, const int* in_sizes, int n_in,
                              void* d_out, int out_size, void* d_ws, size_t ws_size,
                              hipStream_t stream) {
  const float* qn  = (const float*)d_in[0];
  const float* qp  = (const float*)d_in[1];
  const float* kv  = (const float*)d_in[2];
  const float* pe  = (const float*)d_in[3];
  const float* wkv = (const float*)d_in[4];
  const float* wo  = (const float*)d_in[5];
  const int*   pcl = (const int*)d_in[6];
  float* out = (float*)d_out;

  char* ws = (char*)d_ws;
  u16* Qc   = (u16*)(ws);                 // [H][T][192]  12,582,912 B
  u16* Kc   = (u16*)(ws + 12582912);      // [H][S][192]  12,582,912 B
  u16* Vt   = (u16*)(ws + 25165824);      // [H][128][S]   8,388,608 B
  u16* Ob   = (u16*)(ws + 33554432);      // [T][H*128]    8,388,608 B
  u16* kvb  = (u16*)(ws + 41943040);      // [S][512]      2,097,152 B
  u16* wkvb = (u16*)(ws + 44040192);      // [4096][512]   4,194,304 B
  u16* wob  = (u16*)(ws + 48234496);      // [2048][2048]  8,388,608 B

  k_build<<<2048, 256, 0, stream>>>(qn, qp, pe, kv, wkv, wo, Qc, Kc, kvb, wkvb, wob);
  k_expand<<<dim3(16, 32), 256, 0, stream>>>(kvb, wkvb, Kc, Vt);
  k_attn<<<dim3(32, 16), 512, 0, stream>>>(Qc, Kc, Vt, Ob, pcl);
  k_proj<<<dim3(32, 16), 256, 0, stream>>>(Ob, wob, out);
}